// Round 5
// baseline (59389.905 us; speedup 1.0000x reference)
//
#include <hip/hip_runtime.h>
#include <cstdint>
#include <cstddef>

#define SEQ 512
#define BAT 64
#define DIM 1024
#define HID 1024
#define NLAYER 2
#define NGATE 4096  // 4*HID
#define EPS_LN 1e-5f

// ---------------- setup ----------------

__global__ void init_hc_kernel(const float* __restrict__ h0,
                               const float* __restrict__ c0,
                               float* __restrict__ hbuf,
                               float* __restrict__ cbuf) {
    int i = blockIdx.x * blockDim.x + threadIdx.x; // 2*64*1024 total
    hbuf[i] = h0[i];
    cbuf[i] = c0[i];
}

// ---------------- per-step gates GEMM (pure fp32 VALU) ----------------
// Block (nt, ks): part[ks][b][n] for n in [nt*64, nt*64+64), one 512-wide K
// slice. ks 0,1 -> x half (A0 + Wx rows 0/512); ks 2,3 -> h half (A1 + Wh).
__global__ __launch_bounds__(256) void gates_f32_kernel(
    const float* __restrict__ A0,   // [64][1024] fp32 (x_t or y_prev_t)
    const float* __restrict__ A1,   // [64][1024] fp32 (h)
    const float* __restrict__ Wx,   // [1024][4096] fp32 (layer slice)
    const float* __restrict__ Wh,   // [1024][4096] fp32 (layer slice)
    float* __restrict__ part)       // [4][64][4096]
{
    __shared__ float a_lds[64][65];  // [k_chunk][batch], +1 pad

    int nt = blockIdx.x;   // 0..63
    int ks = blockIdx.y;   // 0..3
    int tid = threadIdx.x;
    int n0 = nt * 64;
    int kbase = (ks & 1) * 512;
    const float* Wsrc = (ks < 2) ? Wx : Wh;
    const float* Asrc = (ks < 2) ? A0 : A1;

    int nl = tid & 63;     // n within tile (also k-index during staging)
    int bg = tid >> 6;     // batch group 0..3 (16 batches each)

    float acc[16];
    #pragma unroll
    for (int i = 0; i < 16; i++) acc[i] = 0.f;

    for (int kc = 0; kc < 512; kc += 64) {
        __syncthreads();
        // stage A^T chunk: a_lds[k][b] = A[b][kbase+kc+k]
        int kst = tid & 63;
        int b0  = (tid >> 6) * 16;
        #pragma unroll
        for (int m = 0; m < 16; m++) {
            a_lds[kst][b0 + m] = Asrc[(size_t)(b0 + m) * 1024 + kbase + kc + kst];
        }
        __syncthreads();

        const float* wp = Wsrc + (size_t)(kbase + kc) * 4096 + n0 + nl;
        #pragma unroll 8
        for (int k = 0; k < 64; k++) {
            float w = wp[(size_t)k * 4096];          // coalesced across nl
            #pragma unroll
            for (int bb = 0; bb < 16; bb++)          // LDS broadcast reads
                acc[bb] += a_lds[k][bg * 16 + bb] * w;
        }
    }

    float* p = part + (size_t)ks * (BAT * NGATE);
    #pragma unroll
    for (int bb = 0; bb < 16; bb++)
        p[(size_t)(bg * 16 + bb) * NGATE + n0 + nl] = acc[bb];
}

// ---------------- per-step LN + cell update ----------------
__global__ __launch_bounds__(1024) void update_kernel(
    const float* __restrict__ part,    // [4][64][4096]
    const float* __restrict__ bias,    // [4096]  (layer slice)
    const float* __restrict__ gamma,   // [4][1024]
    const float* __restrict__ beta,    // [4][1024]
    float* __restrict__ cbuf,          // [64][1024]
    float* __restrict__ hbuf,          // [64][1024]
    float* __restrict__ y_out,         // d_out ys slot t
    float* __restrict__ hs_out,        // t==S-1: d_out hs slot, else null
    float* __restrict__ cs_out)
{
    int b = blockIdx.x;
    int j = threadIdx.x;
    float raw[4], s[4], q[4];
    #pragma unroll
    for (int g = 0; g < 4; g++) {
        int col = g * 1024 + j;
        float v = part[(size_t)b * 4096 + col]
                + part[262144 + (size_t)b * 4096 + col]
                + part[524288 + (size_t)b * 4096 + col]
                + part[786432 + (size_t)b * 4096 + col]
                + bias[col];
        raw[g] = v; s[g] = v; q[g] = v * v;
    }
    #pragma unroll
    for (int off = 32; off > 0; off >>= 1) {
        #pragma unroll
        for (int g = 0; g < 4; g++) {
            s[g] += __shfl_down(s[g], off);
            q[g] += __shfl_down(q[g], off);
        }
    }
    __shared__ float red[16][8];
    __shared__ float stats[8];
    int wave = j >> 6, lane = j & 63;
    if (lane == 0) {
        #pragma unroll
        for (int g = 0; g < 4; g++) { red[wave][g] = s[g]; red[wave][4 + g] = q[g]; }
    }
    __syncthreads();
    if (j == 0) {
        float ts[8] = {0,0,0,0,0,0,0,0};
        for (int w = 0; w < 16; w++)
            for (int g = 0; g < 8; g++) ts[g] += red[w][g];
        #pragma unroll
        for (int g = 0; g < 4; g++) {
            float mu  = ts[g] * (1.0f / 1024.0f);
            float var = ts[4 + g] * (1.0f / 1024.0f) - mu * mu;
            stats[g] = mu;
            stats[4 + g] = rsqrtf(fmaxf(var, 0.0f) + EPS_LN);
        }
    }
    __syncthreads();
    float gh[4];
    #pragma unroll
    for (int g = 0; g < 4; g++) {
        int col = g * 1024 + j;
        gh[g] = (raw[g] - stats[g]) * stats[4 + g] * gamma[col] + beta[col];
    }
    float c_old = cbuf[b * 1024 + j];
    float ig = 1.f / (1.f + __expf(-gh[0]));
    float fg = 1.f / (1.f + __expf(-gh[1]));
    float og = 1.f / (1.f + __expf(-gh[2]));
    float c_new = fg * c_old + ig * tanhf(gh[3]);
    float h_new = og * tanhf(c_new);
    cbuf[b * 1024 + j] = c_new;
    hbuf[b * 1024 + j] = h_new;
    y_out[b * 1024 + j] = h_new;
    if (hs_out) { hs_out[b * 1024 + j] = h_new; cs_out[b * 1024 + j] = c_new; }
}

// ---------------- launch ----------------

extern "C" void kernel_launch(void* const* d_in, const int* in_sizes, int n_in,
                              void* d_out, int out_size, void* d_ws, size_t ws_size,
                              hipStream_t stream) {
    // All fp32, per the reference.
    const float* inputs = (const float*)d_in[0]; // (512,64,1024)
    const float* h0     = (const float*)d_in[1]; // (2,64,1024)
    const float* c0     = (const float*)d_in[2]; // (2,64,1024)
    const float* wx     = (const float*)d_in[3]; // (2,1024,4096)
    const float* wh     = (const float*)d_in[4]; // (2,1024,4096)
    const float* bias   = (const float*)d_in[5]; // (2,4096)
    const float* gamma  = (const float*)d_in[6]; // (2,4,1024)
    const float* beta   = (const float*)d_in[7]; // (2,4,1024)
    float* dout = (float*)d_out;

    // lean workspace: 5 MiB total
    float* part  = (float*)d_ws;          // 4*64*4096 f32 = 4 MiB
    float* hbuf  = part + 1048576;        // 2*64*1024 f32 = 512 KiB
    float* cbuf  = hbuf + 131072;         // 2*64*1024 f32 = 512 KiB

    init_hc_kernel<<<512, 256, 0, stream>>>(h0, c0, hbuf, cbuf);

    const int BH = BAT * HID;         // 65536
    const int XOUT = SEQ * BAT * HID; // 33,554,432
    const size_t WL = (size_t)1024 * 4096; // per-layer weight stride
    for (int t = 0; t < SEQ; t++) {
        for (int l = 0; l < NLAYER; l++) {
            // layer 0 reads x_t; layer 1 reads y0_t just written into d_out slot t
            const float* a0 = (l == 0) ? (inputs + (size_t)t * BH)
                                       : (dout + (size_t)t * BH);
            gates_f32_kernel<<<dim3(64, 4), 256, 0, stream>>>(
                a0, hbuf + l * BH, wx + l * WL, wh + l * WL, part);
            update_kernel<<<64, 1024, 0, stream>>>(
                part,
                bias + l * 4096, gamma + l * 4096, beta + l * 4096,
                cbuf + l * BH, hbuf + l * BH,
                dout + (size_t)t * BH,   // l0 writes y0_t, l1 overwrites with y1_t
                (t == SEQ - 1) ? (dout + XOUT + l * BH) : nullptr,
                (t == SEQ - 1) ? (dout + XOUT + NLAYER * BH + l * BH) : nullptr);
        }
    }
}